// Round 4
// baseline (471.358 us; speedup 1.0000x reference)
//
#include <hip/hip_runtime.h>
#include <hip/hip_cooperative_groups.h>
#include <math.h>

namespace cg = cooperative_groups;

// Problem constants
#define B_N 2048
#define T_N 128
#define C_N 3
#define J_N 25
#define E_N 64
#define TC  (T_N*C_N)    // 384 rows per batch
#define TCJ (TC*J_N)     // 9600 floats per batch
#define NQ4 (TCJ/4)      // 2400 float4 per batch
#define NC  256          // contracted size (ncomp <= 256 after 3 unions)

// Workspace layout (float offsets). ~17.4 MiB.
#define D_OFF      0                       // D [2048*2048] f32 (raw-h distances)
#define H_OFF      (B_N*B_N)               // h [2048*25]
#define BLO_OFF    (H_OFF + B_N*J_N)       // per-block lo [2048]
#define BHI_OFF    (BLO_OFF + B_N)         // per-block hi [2048]
#define DEATHS_OFF (BHI_OFF + B_N)         // f32 deaths[2047]
#define BEST_OFF   (DEATHS_OFF + B_N)      // u64 best[2][2048] (even -> 8B aligned)
#define COMP_OFF   (BEST_OFF + 4*B_N)      // (kept for layout; unused now)
#define GC_OFF     (COMP_OFF + 2*B_N)      // u32 gcnt[2]
#define DC_OFF     (GC_OFF + 2)            // u32 Dc[256*256] contracted min-dist (f32 bits)

typedef unsigned long long u64;
#define U64MAX 0xFFFFFFFFFFFFFFFFull
#define U32INF 0xFFFFFFFFu

// One block per batch. Coalesced float4 grid-stride (stride 250 preserves
// j-residue mod 25), register accumulate, tiny LDS reduce. Per-block lo/hi.
__global__ void __launch_bounds__(256) k_reduce(const float* __restrict__ x,
                                                float* __restrict__ ws) {
    __shared__ float4 part[250];
    __shared__ float S[100];
    __shared__ float Mj[25];
    const int t = threadIdx.x, b = blockIdx.x;
    const float4* x4 = (const float4*)(x + (size_t)b * TCJ);
    if (t < 250) {
        float4 a; a.x = a.y = a.z = a.w = 0.f;
        for (int idx = t; idx < NQ4; idx += 250) {
            float4 v = x4[idx];
            a.x += v.x; a.y += v.y; a.z += v.z; a.w += v.w;
        }
        part[t] = a;
    }
    __syncthreads();
    if (t < 25) {
        float4 s = part[t];
        #pragma unroll
        for (int g = 1; g < 10; ++g) {
            float4 v = part[t + 25 * g];
            s.x += v.x; s.y += v.y; s.z += v.z; s.w += v.w;
        }
        S[4*t] = s.x; S[4*t+1] = s.y; S[4*t+2] = s.z; S[4*t+3] = s.w;
    }
    __syncthreads();
    if (t < 25) Mj[t] = (S[t] + S[t+25] + S[t+50] + S[t+75]) * (1.0f / 384.0f);
    __syncthreads();
    if (t < 25) {
        float mj = Mj[t], acc = 0.f;
        #pragma unroll
        for (int i = 0; i < J_N; ++i) { float d = Mj[i] - mj; acc += d * d; }
        float hv = sqrtf(acc);
        ws[H_OFF + b * J_N + t] = hv;
        S[t] = hv;
    }
    __syncthreads();
    if (t == 0) {
        float lo = S[0], hi = S[0];
        #pragma unroll
        for (int i = 1; i < J_N; ++i) { lo = fminf(lo, S[i]); hi = fmaxf(hi, S[i]); }
        ws[BLO_OFF + b] = lo;
        ws[BHI_OFF + b] = hi;
    }
}

// Replicated Boruvka union over LDS comp[]. Reads bin (global best keys),
// merges, appends deaths (blk 0 only), updates comp[] in place and curbase.
// Trailing barrier protects cnt_s against the next union's reset.
#define UNION_PHASE(binp)                                                     \
  {                                                                           \
    if (t == 0) cnt_s = 0u;                                                   \
    cb[t] = U64MAX; cb[t + 1024] = U64MAX;                                    \
    __syncthreads();                                                          \
    for (int i = t; i < B_N; i += 1024) {                                     \
      u64 bk = (binp)[i];                                                     \
      if (bk != U64MAX) atomicMin(&cb[comp[i]], bk);                          \
    }                                                                         \
    __syncthreads();                                                          \
    for (int c = t; c < B_N; c += 1024) {                                     \
      u64 k = cb[c];                                                          \
      unsigned p = (unsigned)c;                                               \
      if (k != U64MAX) {                                                      \
        unsigned a  = (unsigned)((k >> 11) & 0x7FFu);                         \
        unsigned b2 = (unsigned)(k & 0x7FFu);                                 \
        unsigned ca = comp[a], cbv = comp[b2];                                \
        unsigned c2 = (ca == (unsigned)c) ? cbv : ca;                         \
        p = c2;                                                               \
        if (!(cb[c2] == k && c2 < (unsigned)c)) {                             \
          unsigned li = atomicAdd(&cnt_s, 1u);                                \
          if (blk == 0) deaths[curbase + li] = __uint_as_float((unsigned)(k >> 32)); \
        }                                                                     \
      }                                                                       \
      par[c] = p;                                                             \
    }                                                                         \
    __syncthreads();                                                          \
    for (int c = t; c < B_N; c += 1024) {                                     \
      unsigned p = par[c];                                                    \
      if (p != (unsigned)c && par[p] == (unsigned)c && (unsigned)c < p) par[c] = (unsigned)c; \
    }                                                                         \
    __syncthreads();                                                          \
    for (int c = t; c < B_N; c += 1024) {                                     \
      unsigned r2 = par[c];                                                   \
      while (true) { unsigned pr = par[r2]; if (pr == r2) break; r2 = pr; }   \
      par[c] = r2;                                                            \
    }                                                                         \
    __syncthreads();                                                          \
    for (int i = t; i < B_N; i += 1024) comp[i] = par[comp[i]];               \
    __syncthreads();                                                          \
    curbase += cnt_s;                                                         \
    __syncthreads();                                                          \
  }

// Fused cooperative kernel: distance matrix + round-0 scan + 3 Boruvka
// unions (+2 scans) + contraction to Dc[256x256]. 256 blocks x 1024 thr =
// 1 block/CU (112 KB LDS), grid.sync() between grid-wide phases. comp[]
// lives in LDS for the whole kernel; the 100 KB distance staging buffer is
// overlaid with the union/rank/contract scratch. Round bases tracked
// in-register (replicated deterministic counts) - no gcnt round-trips.
__global__ void __launch_bounds__(1024) k_coop(float* __restrict__ ws) {
    cg::grid_group grid = cg::this_grid();
    __shared__ float A[8][26];
    __shared__ u64 part[16];
    __shared__ __align__(16) unsigned comp[B_N];     // 8 KB, persistent
    __shared__ unsigned cnt_s, csum[16];
    __shared__ __align__(16) char ovl[1024 * J_N * 4];  // 100 KB overlay
    u64*      cb    = (u64*)ovl;                     // 16 KB
    unsigned* par   = (unsigned*)(ovl + 16384);      // 8 KB
    unsigned* cflag = (unsigned*)(ovl + 24576);      // 8 KB
    unsigned* pd    = (unsigned*)(ovl + 32768);      // 8 KB  pd[w*NC+j]
    float*    Bsh   = (float*)ovl;                   // 100 KB (phase 0 only)

    const int t = threadIdx.x, blk = blockIdx.x;
    const int lane = t & 63, w = t >> 6;
    const float* h = ws + H_OFF;
    float* deaths = ws + DEATHS_OFF;
    u64* BEST = (u64*)(ws + BEST_OFF);
    float* D = ws + D_OFF;

    // ---- phase 0: dist + per-row min scan (round-2 LDS-staged version) ----
    const int tx = t & 127, grp = t >> 7;   // 8 groups of 128 lanes
    const int row0 = blk * 8;
    if (t < 8 * J_N) A[t / J_N][t % J_N] = h[row0 * J_N + t];
    if (blk < 64) ((unsigned*)(ws + DC_OFF))[blk * 1024 + t] = U32INF;
    comp[t] = (unsigned)t; comp[t + 1024] = (unsigned)(t + 1024);
    const int srow = row0 + grp;
    float ar[J_N];
    u64 bestk = U64MAX;
    for (int mt = 0; mt < 2; ++mt) {
        __syncthreads();   // protect Bsh (and cover A/comp on mt=0)
        for (int idx = t; idx < 1024 * J_N; idx += 1024)
            Bsh[idx] = h[mt * 1024 * J_N + idx];
        __syncthreads();
        if (mt == 0) {
            #pragma unroll
            for (int k = 0; k < J_N; ++k) ar[k] = A[grp][k];
        }
        #pragma unroll 2
        for (int cc = 0; cc < 8; ++cc) {
            const int lcol = cc * 128 + tx;
            const int col = mt * 1024 + lcol;
            const float* bp = &Bsh[lcol * J_N];
            float acc = 0.f;
            #pragma unroll
            for (int k = 0; k < J_N; ++k) { float d = ar[k] - bp[k]; acc += d * d; }
            float dist = sqrtf(fmaxf(acc, 1e-12f));
            D[(size_t)srow * B_N + col] = dist;
            if (col != srow) {
                unsigned a = min((unsigned)srow, (unsigned)col);
                unsigned b2 = max((unsigned)srow, (unsigned)col);
                u64 key = ((u64)__float_as_uint(dist) << 32) | (a << 11) | b2;
                if (key < bestk) bestk = key;
            }
        }
    }
    #pragma unroll
    for (int off = 32; off; off >>= 1) {
        u64 o = __shfl_down(bestk, off);
        if (o < bestk) bestk = o;
    }
    if ((t & 63) == 0) part[t >> 6] = bestk;
    __syncthreads();
    if (t < 8) {
        u64 a = part[2 * t], b = part[2 * t + 1];
        BEST[row0 + t] = a < b ? a : b;
    }
    __threadfence();
    grid.sync();

    // ---- rounds 0,1: union + scan (reuse pruning) ----
    unsigned curbase = 0u;
    bool done = false;
    for (int r = 0; r < 2; ++r) {
        const u64* bin = BEST + (r & 1) * B_N;
        u64* bout = BEST + ((r & 1) ^ 1) * B_N;
        if (!done) {
            UNION_PHASE(bin);
            if (curbase >= B_N - 1) {
                done = true;
            } else if (w < 8) {
                const int row = blk * 8 + w;
                const unsigned ci = comp[row];
                u64 prev = bin[row];
                unsigned pa = (unsigned)((prev >> 11) & 0x7FFu);
                unsigned pb = (unsigned)(prev & 0x7FFu);
                unsigned jo = (pa == (unsigned)row) ? pb : pa;
                if (comp[jo] != ci) {          // still outgoing -> still the min
                    if (lane == 0) bout[row] = prev;
                } else {
                    const float4* row4 = (const float4*)(D + (size_t)row * B_N);
                    const uint4* comp4 = (const uint4*)comp;
                    u64 best = U64MAX;
                    #pragma unroll
                    for (int k = 0; k < 8; ++k) {
                        const int q = k * 64 + lane;
                        float4 w4 = row4[q];
                        uint4  c4 = comp4[q];
                        const unsigned j0 = (unsigned)(q * 4);
                        float wv[4] = {w4.x, w4.y, w4.z, w4.w};
                        unsigned cv[4] = {c4.x, c4.y, c4.z, c4.w};
                        #pragma unroll
                        for (int m = 0; m < 4; ++m) {
                            if (cv[m] != ci) {
                                unsigned j = j0 + m;
                                unsigned a = min((unsigned)row, j), b2 = max((unsigned)row, j);
                                u64 key = ((u64)__float_as_uint(wv[m]) << 32) | (a << 11) | b2;
                                if (key < best) best = key;
                            }
                        }
                    }
                    #pragma unroll
                    for (int off = 32; off; off >>= 1) {
                        u64 o = __shfl_down(best, off);
                        if (o < best) best = o;
                    }
                    if (lane == 0) bout[row] = best;
                }
            }
        }
        __threadfence();
        grid.sync();
    }

    // ---- round 3: union (bin = BEST parity 0) + contraction ----
    if (!done) {
        UNION_PHASE(BEST);
    }
    if (blk == 0 && t == 0) {
        unsigned* gcnt = (unsigned*)(ws + GC_OFF);
        gcnt[0] = curbase; gcnt[1] = curbase;
    }
    if (curbase >= B_N - 1) return;   // converged: finish kernel skips Boruvka

    // ---- rank map (deterministic across blocks) ----
    cflag[t] = 0u; cflag[t + 1024] = 0u;
    __syncthreads();
    cflag[comp[t]] = 1u; cflag[comp[t + 1024]] = 1u;
    __syncthreads();
    unsigned f0 = cflag[2 * t], f1 = cflag[2 * t + 1];
    unsigned s = f0 + f1, sc = s;
    #pragma unroll
    for (int off = 1; off < 64; off <<= 1) {
        unsigned v = __shfl_up(sc, off);
        if (lane >= off) sc += v;
    }
    if (lane == 63) csum[w] = sc;
    __syncthreads();
    if (t < 16) {
        unsigned v = csum[t], acc = v;
        #pragma unroll
        for (int off = 1; off < 16; off <<= 1) {
            unsigned u2 = __shfl_up(acc, off);
            if (t >= off) acc += u2;
        }
        csum[t] = acc - v;   // exclusive
    }
    __syncthreads();
    unsigned off0 = csum[w] + (sc - s);
    __syncthreads();
    if (f0) cflag[2 * t] = off0;
    if (f1) cflag[2 * t + 1] = off0 + f0;
    __syncthreads();

    // ---- contract this block's 8 rows into pd[8][256] -> global Dc ----
    pd[t] = U32INF; pd[t + 1024] = U32INF;
    __syncthreads();
    const int crow = blk * 8 + w;
    unsigned ci2 = 0u;
    if (w < 8) {
        ci2 = comp[crow];
        const float4* row4 = (const float4*)(D + (size_t)crow * B_N);
        const uint4* comp4 = (const uint4*)comp;
        #pragma unroll
        for (int k = 0; k < 8; ++k) {
            const int q = k * 64 + lane;
            float4 w4 = row4[q];
            uint4  c4 = comp4[q];
            float wv[4] = {w4.x, w4.y, w4.z, w4.w};
            unsigned cv[4] = {c4.x, c4.y, c4.z, c4.w};
            #pragma unroll
            for (int m = 0; m < 4; ++m) {
                if (cv[m] != ci2) atomicMin(&pd[w * NC + cflag[cv[m]]], __float_as_uint(wv[m]));
            }
        }
    }
    __syncthreads();
    if (w < 8) {
        unsigned* gDc = (unsigned*)(ws + DC_OFF);
        const unsigned ri = cflag[ci2];
        for (int j2 = lane; j2 < NC; j2 += 64) {
            unsigned v = pd[w * NC + j2];
            if (v != U32INF) atomicMin(&gDc[ri * NC + j2], v);
        }
    }
}

// Finish: in-LDS Boruvka on the contracted matrix with bf16-quantized
// weights (top-16 f32 bits, monotone truncation), bounded by the ACTUAL
// component count ncr = 2048 - gcnt[0] (<= 256). Then the fused structure
// layer.
__global__ void __launch_bounds__(1024) k_finishstruct(float* __restrict__ ws,
                                                       const float* __restrict__ centres,
                                                       const float* __restrict__ sharp,
                                                       float* __restrict__ out) {
    __shared__ unsigned short Dcs[NC * NC];   // 128 KB
    __shared__ u64 cbf[NC];
    __shared__ unsigned parf[NC], ccomp[NC];
    __shared__ unsigned cnt_s, base_s;
    __shared__ float redlo[16], redhi[16];
    const int t = threadIdx.x;
    const int lane = t & 63, w = t >> 6;
    float* deaths = ws + DEATHS_OFF;
    const unsigned base0 = ((const unsigned*)(ws + GC_OFF))[0];

    if (base0 < B_N - 1) {
        const unsigned ncr = (unsigned)B_N - base0;   // remaining components <= 256
        const unsigned* gDc = (const unsigned*)(ws + DC_OFF);
        for (unsigned idx = (unsigned)t; idx < ncr * NC; idx += 1024u)
            Dcs[idx] = (unsigned short)(gDc[idx] >> 16);   // U32INF -> 0xFFFF
        if (t < NC) ccomp[t] = (unsigned)t;
        if (t == 0) base_s = base0;
        __syncthreads();
        const int HH = (int)((ncr + 63u) >> 6);           // col chunks of 64
        for (int iter = 0; iter < 8; ++iter) {
            if (t < NC) cbf[t] = U64MAX;
            if (t == 0) cnt_s = 0u;
            __syncthreads();
            // scan: rows interleaved across waves so small ncr stays balanced
            for (unsigned r = (unsigned)w; r < ncr; r += 16u) {
                const unsigned cc = ccomp[r];
                u64 key = U64MAX;
                for (int hh = 0; hh < HH; ++hh) {
                    const unsigned c = (unsigned)lane + (unsigned)hh * 64u;
                    unsigned wv = Dcs[r * NC + c];
                    if (wv != 0xFFFFu && ccomp[c] != cc) {
                        unsigned a = min(r, c);
                        unsigned b2 = max(r, c);
                        u64 k2 = ((u64)wv << 32) | (a << 8) | b2;
                        if (k2 < key) key = k2;
                    }
                }
                #pragma unroll
                for (int off = 32; off; off >>= 1) {
                    u64 o = __shfl_down(key, off);
                    if (o < key) key = o;
                }
                if (lane == 0 && key != U64MAX) atomicMin(&cbf[cc], key);
            }
            __syncthreads();
            bool add = false; float dw = 0.f;
            if (t < NC) {
                u64 k = cbf[t];
                unsigned p = (unsigned)t;
                if (k != U64MAX) {
                    unsigned a = (unsigned)((k >> 8) & 255u), b2 = (unsigned)(k & 255u);
                    unsigned ca = ccomp[a], cbv = ccomp[b2];
                    unsigned c2 = (ca == (unsigned)t) ? cbv : ca;
                    p = c2;
                    if (!(cbf[c2] == k && c2 < (unsigned)t)) {
                        add = true;
                        dw = __uint_as_float((unsigned)(k >> 32) << 16);
                    }
                }
                parf[t] = p;
            }
            __syncthreads();
            if (t < NC) {
                unsigned pp = parf[t];
                if (pp != (unsigned)t && parf[pp] == (unsigned)t && (unsigned)t < pp) parf[t] = (unsigned)t;
            }
            __syncthreads();
            if (t < NC) {
                unsigned r2 = parf[t];
                while (parf[r2] != r2) r2 = parf[r2];
                parf[t] = r2;
            }
            __syncthreads();
            if (t < NC) {
                if (add) { unsigned li = atomicAdd(&cnt_s, 1u); deaths[base_s + li] = dw; }
                ccomp[t] = parf[ccomp[t]];
            }
            __syncthreads();
            if (t == 0) base_s += cnt_s;
            __syncthreads();
            if (base_s >= B_N - 1) break;
        }
        __syncthreads();
    }

    // ---- struct phase ----
    float lo = INFINITY, hi = -INFINITY;
    #pragma unroll
    for (int i = t; i < B_N; i += 1024) {
        lo = fminf(lo, ws[BLO_OFF + i]);
        hi = fmaxf(hi, ws[BHI_OFF + i]);
    }
    #pragma unroll
    for (int off = 32; off; off >>= 1) {
        lo = fminf(lo, __shfl_down(lo, off));
        hi = fmaxf(hi, __shfl_down(hi, off));
    }
    if (lane == 0) { redlo[w] = lo; redhi[w] = hi; }
    __syncthreads();
    lo = redlo[0]; hi = redhi[0];
    #pragma unroll
    for (int k = 1; k < 16; ++k) { lo = fminf(lo, redlo[k]); hi = fmaxf(hi, redhi[k]); }
    float rng = hi - lo;
    float rinv = (rng > 1e-8f) ? 1.0f / rng : 0.0f;

    for (int e = w; e < E_N; e += 16) {
        const float c0 = centres[e * 2], c1 = centres[e * 2 + 1];
        const float s0 = sharp[e * 2],   s1 = sharp[e * 2 + 1];
        const float s1sq = s1 * s1;
        float acc = 0.f;
        for (int p = lane; p < B_N - 1; p += 64) {
            float d = deaths[p] * rinv - c1;
            acc += expf(-s1sq * d * d);
        }
        #pragma unroll
        for (int off = 32; off; off >>= 1) acc += __shfl_down(acc, off);
        if (lane == 0) out[e] = expf(-s0 * s0 * c0 * c0) * acc;
    }
}

extern "C" void kernel_launch(void* const* d_in, const int* in_sizes, int n_in,
                              void* d_out, int out_size, void* d_ws, size_t ws_size,
                              hipStream_t stream) {
    const float* x       = (const float*)d_in[0];
    const float* centres = (const float*)d_in[1];
    const float* sharp   = (const float*)d_in[2];
    float* out = (float*)d_out;
    float* ws  = (float*)d_ws;

    hipLaunchKernelGGL(k_reduce, dim3(B_N), dim3(256), 0, stream, x, ws);
    void* cargs[] = { (void*)&ws };
    hipLaunchCooperativeKernel((const void*)k_coop, dim3(256), dim3(1024),
                               cargs, 0, stream);
    hipLaunchKernelGGL(k_finishstruct, dim3(1), dim3(1024), 0, stream, ws, centres, sharp, out);
}

// Round 6
// 170.248 us; speedup vs baseline: 2.7687x; 2.7687x over previous
//
#include <hip/hip_runtime.h>
#include <math.h>

// Problem constants
#define B_N 2048
#define T_N 128
#define C_N 3
#define J_N 25
#define E_N 64
#define TC  (T_N*C_N)    // 384 rows per batch
#define TCJ (TC*J_N)     // 9600 floats per batch
#define NQ4 (TCJ/4)      // 2400 float4 per batch
#define NC  256          // contracted size (ncomp <= 256 after 3 unions)

// Workspace layout (float offsets). ~17.4 MiB.
#define D_OFF      0                       // D [2048*2048] f32 (raw-h distances)
#define H_OFF      (B_N*B_N)               // h [2048*25]
#define BLO_OFF    (H_OFF + B_N*J_N)       // per-block lo [2048]
#define BHI_OFF    (BLO_OFF + B_N)         // per-block hi [2048]
#define DEATHS_OFF (BHI_OFF + B_N)         // f32 deaths[2047]
#define BEST_OFF   (DEATHS_OFF + B_N)      // u64 best[2][2048] (even -> 8B aligned)
#define COMP_OFF   (BEST_OFF + 4*B_N)      // u32 comp[2][2048]
#define GC_OFF     (COMP_OFF + 2*B_N)      // u32 gcnt[2]
#define DC_OFF     (GC_OFF + 2)            // u32 Dc[256*256] contracted min-dist (f32 bits)

typedef unsigned long long u64;
#define U64MAX 0xFFFFFFFFFFFFFFFFull
#define U32INF 0xFFFFFFFFu

// One block per batch. Coalesced float4 grid-stride (stride 250 preserves
// j-residue mod 25), register accumulate, tiny LDS reduce. Per-block lo/hi.
__global__ void __launch_bounds__(256) k_reduce(const float* __restrict__ x,
                                                float* __restrict__ ws) {
    __shared__ float4 part[250];
    __shared__ float S[100];
    __shared__ float Mj[25];
    const int t = threadIdx.x, b = blockIdx.x;
    const float4* x4 = (const float4*)(x + (size_t)b * TCJ);
    if (t < 250) {
        float4 a; a.x = a.y = a.z = a.w = 0.f;
        for (int idx = t; idx < NQ4; idx += 250) {
            float4 v = x4[idx];
            a.x += v.x; a.y += v.y; a.z += v.z; a.w += v.w;
        }
        part[t] = a;
    }
    __syncthreads();
    if (t < 25) {
        float4 s = part[t];
        #pragma unroll
        for (int g = 1; g < 10; ++g) {
            float4 v = part[t + 25 * g];
            s.x += v.x; s.y += v.y; s.z += v.z; s.w += v.w;
        }
        S[4*t] = s.x; S[4*t+1] = s.y; S[4*t+2] = s.z; S[4*t+3] = s.w;
    }
    __syncthreads();
    if (t < 25) Mj[t] = (S[t] + S[t+25] + S[t+50] + S[t+75]) * (1.0f / 384.0f);
    __syncthreads();
    if (t < 25) {
        float mj = Mj[t], acc = 0.f;
        #pragma unroll
        for (int i = 0; i < J_N; ++i) { float d = Mj[i] - mj; acc += d * d; }
        float hv = sqrtf(acc);
        ws[H_OFF + b * J_N + t] = hv;
        S[t] = hv;
    }
    __syncthreads();
    if (t == 0) {
        float lo = S[0], hi = S[0];
        #pragma unroll
        for (int i = 1; i < J_N; ++i) { lo = fminf(lo, S[i]); hi = fmaxf(hi, S[i]); }
        ws[BLO_OFF + b] = lo;
        ws[BHI_OFF + b] = hi;
    }
}

// Fused dist + round-0 scan. 256 blocks x 8 rows (full GPU). Each row is
// handled by a 128-lane group (2 waves); two 1024-column mega-tiles of h
// staged in LDS; A-row in registers. Running min edge key in-register ->
// shuffle-reduce -> LDS pair merge -> best[0][row]. Seeds comp/gcnt/Dc.
__global__ void __launch_bounds__(1024) k_distscan(float* __restrict__ ws) {
    __shared__ float A[8][26];
    __shared__ float Bsh[1024 * J_N];   // 100 KB
    __shared__ u64 part[16];
    const int t = threadIdx.x, blk = blockIdx.x;
    const int tx = t & 127, grp = t >> 7;   // 8 groups of 128 lanes
    const float* h = ws + H_OFF;
    const int row0 = blk * 8;
    if (t < 8 * J_N) A[t / J_N][t % J_N] = h[row0 * J_N + t];
    if (blk < 64) ((unsigned*)(ws + DC_OFF))[blk * 1024 + t] = U32INF;
    if (blk == 0) {
        unsigned* gc = (unsigned*)(ws + COMP_OFF);
        gc[t] = (unsigned)t; gc[t + 1024] = (unsigned)(t + 1024);
        if (t == 0) { ((unsigned*)(ws + GC_OFF))[0] = 0u; ((unsigned*)(ws + GC_OFF))[1] = 0u; }
    }
    const int row = row0 + grp;
    float ar[J_N];
    u64 bestk = U64MAX;
    float* D = ws + D_OFF;
    for (int mt = 0; mt < 2; ++mt) {
        __syncthreads();   // protect Bsh (and cover A on mt=0)
        for (int idx = t; idx < 1024 * J_N; idx += 1024)
            Bsh[idx] = h[mt * 1024 * J_N + idx];
        __syncthreads();
        if (mt == 0) {
            #pragma unroll
            for (int k = 0; k < J_N; ++k) ar[k] = A[grp][k];
        }
        #pragma unroll 2
        for (int cc = 0; cc < 8; ++cc) {
            const int lcol = cc * 128 + tx;
            const int col = mt * 1024 + lcol;
            const float* bp = &Bsh[lcol * J_N];
            float acc = 0.f;
            #pragma unroll
            for (int k = 0; k < J_N; ++k) { float d = ar[k] - bp[k]; acc += d * d; }
            float dist = sqrtf(fmaxf(acc, 1e-12f));
            D[(size_t)row * B_N + col] = dist;
            if (col != row) {
                unsigned a = min((unsigned)row, (unsigned)col);
                unsigned b2 = max((unsigned)row, (unsigned)col);
                u64 key = ((u64)__float_as_uint(dist) << 32) | (a << 11) | b2;
                if (key < bestk) bestk = key;
            }
        }
    }
    #pragma unroll
    for (int off = 32; off; off >>= 1) {
        u64 o = __shfl_down(bestk, off);
        if (o < bestk) bestk = o;
    }
    if ((t & 63) == 0) part[t >> 6] = bestk;
    __syncthreads();
    if (t < 8) {
        u64 a = part[2 * t], b = part[2 * t + 1];
        ((u64*)(ws + BEST_OFF))[row0 + t] = a < b ? a : b;
    }
}

// One Boruvka round: replicated-in-LDS union of best[par_in], then scan with
// the fresh LDS comp -> best[par_in^1]. Reuse pruning: if a row's previous
// best edge is still outgoing, it remains the row min. 256 blocks x 8 rows
// (waves 8-15 exit before the scan). blk0 persists state.
__global__ void __launch_bounds__(1024) k_round(float* __restrict__ ws, int par_in) {
    unsigned* gcnt = (unsigned*)(ws + GC_OFF);
    const unsigned base = gcnt[par_in];
    if (base >= B_N - 1) return;   // converged: stub
    __shared__ __align__(16) unsigned comp[B_N];  // 8 KB
    __shared__ u64 cb[B_N];                       // 16 KB
    __shared__ unsigned par[B_N];                 // 8 KB
    __shared__ unsigned cnt_s;
    const int t = threadIdx.x, blk = blockIdx.x;
    const unsigned* gcomp_in = (const unsigned*)(ws + COMP_OFF) + par_in * B_N;
    unsigned* gcomp_out = (unsigned*)(ws + COMP_OFF) + (par_in ^ 1) * B_N;
    const u64* bin = (const u64*)(ws + BEST_OFF) + par_in * B_N;
    u64* bout = (u64*)(ws + BEST_OFF) + (par_in ^ 1) * B_N;
    float* deaths = ws + DEATHS_OFF;

    if (t == 0) cnt_s = 0u;
    comp[t] = gcomp_in[t]; comp[t + 1024] = gcomp_in[t + 1024];
    cb[t] = U64MAX; cb[t + 1024] = U64MAX;
    __syncthreads();
    #pragma unroll
    for (int i = t; i < B_N; i += 1024) {
        u64 bk = bin[i];
        if (bk != U64MAX) atomicMin(&cb[comp[i]], bk);
    }
    __syncthreads();
    #pragma unroll
    for (int c = t; c < B_N; c += 1024) {
        u64 k = cb[c];
        unsigned p = (unsigned)c;
        if (k != U64MAX) {
            unsigned a  = (unsigned)((k >> 11) & 0x7FFu);
            unsigned b2 = (unsigned)(k & 0x7FFu);
            unsigned ca = comp[a], cbv = comp[b2];
            unsigned c2 = (ca == (unsigned)c) ? cbv : ca;
            p = c2;
            if (!(cb[c2] == k && c2 < (unsigned)c)) {
                unsigned li = atomicAdd(&cnt_s, 1u);
                if (blk == 0) deaths[base + li] = __uint_as_float((unsigned)(k >> 32));
            }
        }
        par[c] = p;
    }
    __syncthreads();
    #pragma unroll
    for (int c = t; c < B_N; c += 1024) {
        unsigned p = par[c];
        if (p != (unsigned)c && par[p] == (unsigned)c && (unsigned)c < p) par[c] = (unsigned)c;
    }
    __syncthreads();
    #pragma unroll
    for (int c = t; c < B_N; c += 1024) {
        unsigned r = par[c];
        while (true) { unsigned pr = par[r]; if (pr == r) break; r = pr; }
        par[c] = r;
    }
    __syncthreads();
    #pragma unroll
    for (int i = t; i < B_N; i += 1024) comp[i] = par[comp[i]];
    __syncthreads();
    const unsigned newbase = base + cnt_s;
    if (blk == 0) {
        gcomp_out[t] = comp[t]; gcomp_out[t + 1024] = comp[t + 1024];
        if (t == 0) { gcnt[par_in ^ 1] = newbase; if (newbase >= B_N - 1) gcnt[par_in] = newbase; }
    }
    if (newbase >= B_N - 1) return;

    // ---- scan (one wave per row) with reuse pruning ----
    const int w = t >> 6, lane = t & 63;
    if (w >= 8) return;                // waves 8-15 done (no barriers below)
    const int row = blk * 8 + w;
    const unsigned ci = comp[row];
    u64 prev = bin[row];
    {
        unsigned pa = (unsigned)((prev >> 11) & 0x7FFu);
        unsigned pb = (unsigned)(prev & 0x7FFu);
        unsigned jo = (pa == (unsigned)row) ? pb : pa;
        if (comp[jo] != ci) {          // still outgoing -> still the min
            if (lane == 0) bout[row] = prev;
            return;                    // wave-uniform exit
        }
    }
    const float4* row4 = (const float4*)(ws + D_OFF + (size_t)row * B_N);
    const uint4* comp4 = (const uint4*)comp;
    u64 best = U64MAX;
    #pragma unroll
    for (int k = 0; k < 8; ++k) {
        const int q = k * 64 + lane;
        float4 w4 = row4[q];
        uint4  c4 = comp4[q];
        const unsigned j0 = (unsigned)(q * 4);
        float wv[4] = {w4.x, w4.y, w4.z, w4.w};
        unsigned cv[4] = {c4.x, c4.y, c4.z, c4.w};
        #pragma unroll
        for (int m = 0; m < 4; ++m) {
            if (cv[m] != ci) {
                unsigned j = j0 + m;
                unsigned a = min((unsigned)row, j), b2 = max((unsigned)row, j);
                u64 key = ((u64)__float_as_uint(wv[m]) << 32) | (a << 11) | b2;
                if (key < best) best = key;
            }
        }
    }
    #pragma unroll
    for (int off = 32; off; off >>= 1) {
        u64 o = __shfl_down(best, off);
        if (o < best) best = o;
    }
    if (lane == 0) bout[row] = best;
}

// 3rd union (par_in=0) FUSED with contraction to a 256x256 matrix.
// After the replicated union (ncomp <= 256 guaranteed), build the
// deterministic rank map (prefix scan of root flags), scan this block's 8
// rows into a per-row-local LDS partial pd[8][256] (8 KB), merge via
// distinct-address global atomicMin into Dc[256*256]. 256 blocks.
__global__ void __launch_bounds__(1024) k_round3c(float* __restrict__ ws) {
    unsigned* gcnt = (unsigned*)(ws + GC_OFF);
    const unsigned base = gcnt[0];
    if (base >= B_N - 1) return;   // can't happen before round 4; guard anyway
    __shared__ __align__(16) unsigned comp[B_N];   // 8 KB
    __shared__ u64 cb[B_N];                        // 16 KB
    __shared__ unsigned par[B_N];                  // 8 KB
    __shared__ unsigned cflag[B_N];                // 8 KB
    __shared__ unsigned pd[8][NC];                 // 8 KB partial contracted rows
    __shared__ unsigned cnt_s, csum[16];
    const int t = threadIdx.x, blk = blockIdx.x;
    const unsigned* gcomp_in = (const unsigned*)(ws + COMP_OFF);  // parity 0
    const u64* bin = (const u64*)(ws + BEST_OFF);                 // parity 0
    float* deaths = ws + DEATHS_OFF;

    // ---- phase A: union (identical logic to k_round) ----
    if (t == 0) cnt_s = 0u;
    comp[t] = gcomp_in[t]; comp[t + 1024] = gcomp_in[t + 1024];
    cb[t] = U64MAX; cb[t + 1024] = U64MAX;
    __syncthreads();
    #pragma unroll
    for (int i = t; i < B_N; i += 1024) {
        u64 bk = bin[i];
        if (bk != U64MAX) atomicMin(&cb[comp[i]], bk);
    }
    __syncthreads();
    #pragma unroll
    for (int c = t; c < B_N; c += 1024) {
        u64 k = cb[c];
        unsigned p = (unsigned)c;
        if (k != U64MAX) {
            unsigned a  = (unsigned)((k >> 11) & 0x7FFu);
            unsigned b2 = (unsigned)(k & 0x7FFu);
            unsigned ca = comp[a], cbv = comp[b2];
            unsigned c2 = (ca == (unsigned)c) ? cbv : ca;
            p = c2;
            if (!(cb[c2] == k && c2 < (unsigned)c)) {
                unsigned li = atomicAdd(&cnt_s, 1u);
                if (blk == 0) deaths[base + li] = __uint_as_float((unsigned)(k >> 32));
            }
        }
        par[c] = p;
    }
    __syncthreads();
    #pragma unroll
    for (int c = t; c < B_N; c += 1024) {
        unsigned p = par[c];
        if (p != (unsigned)c && par[p] == (unsigned)c && (unsigned)c < p) par[c] = (unsigned)c;
    }
    __syncthreads();
    #pragma unroll
    for (int c = t; c < B_N; c += 1024) {
        unsigned r = par[c];
        while (true) { unsigned pr = par[r]; if (pr == r) break; r = pr; }
        par[c] = r;
    }
    __syncthreads();
    #pragma unroll
    for (int i = t; i < B_N; i += 1024) comp[i] = par[comp[i]];
    __syncthreads();
    const unsigned newbase = base + cnt_s;
    if (blk == 0 && t == 0) { gcnt[0] = newbase; gcnt[1] = newbase; }
    if (newbase >= B_N - 1) return;

    // ---- phase B: rank map (deterministic across blocks) ----
    cflag[t] = 0u; cflag[t + 1024] = 0u;
    __syncthreads();
    cflag[comp[t]] = 1u; cflag[comp[t + 1024]] = 1u;
    __syncthreads();
    const unsigned lane = t & 63, w = t >> 6;
    unsigned f0 = cflag[2 * t], f1 = cflag[2 * t + 1];
    unsigned s = f0 + f1, sc = s;
    #pragma unroll
    for (int off = 1; off < 64; off <<= 1) {
        unsigned v = __shfl_up(sc, off);
        if (lane >= (unsigned)off) sc += v;
    }
    if (lane == 63) csum[w] = sc;
    __syncthreads();
    if (t < 16) {
        unsigned v = csum[t], acc = v;
        #pragma unroll
        for (int off = 1; off < 16; off <<= 1) {
            unsigned u2 = __shfl_up(acc, off);
            if (t >= off) acc += u2;
        }
        csum[t] = acc - v;   // exclusive
    }
    __syncthreads();
    unsigned off0 = csum[w] + (sc - s);
    __syncthreads();
    if (f0) cflag[2 * t] = off0;
    if (f1) cflag[2 * t + 1] = off0 + f0;
    __syncthreads();

    // ---- phase C: contract this block's 8 rows into pd[8][256] ----
    #pragma unroll
    for (int i = 0; i < 2; ++i) pd[0][i * 1024 + t] = U32INF;
    __syncthreads();
    const int row = blk * 8 + (int)w;
    unsigned ci = 0u;
    if (w < 8) {
        ci = comp[row];
        const float4* row4 = (const float4*)(ws + D_OFF + (size_t)row * B_N);
        const uint4* comp4 = (const uint4*)comp;
        #pragma unroll
        for (int k = 0; k < 8; ++k) {
            const int q = k * 64 + (int)lane;
            float4 w4 = row4[q];
            uint4  c4 = comp4[q];
            float wv[4] = {w4.x, w4.y, w4.z, w4.w};
            unsigned cv[4] = {c4.x, c4.y, c4.z, c4.w};
            #pragma unroll
            for (int m = 0; m < 4; ++m) {
                if (cv[m] != ci) atomicMin(&pd[w][cflag[cv[m]]], __float_as_uint(wv[m]));
            }
        }
    }
    __syncthreads();
    if (w < 8) {
        unsigned* gDc = (unsigned*)(ws + DC_OFF);
        const unsigned ri = cflag[ci];
        for (int j2 = (int)lane; j2 < NC; j2 += 64) {
            unsigned v = pd[w][j2];
            if (v != U32INF) atomicMin(&gDc[ri * NC + j2], v);
        }
    }
}

// Finish: in-LDS Boruvka on the contracted matrix with bf16-quantized
// weights (top-16 f32 bits, monotone truncation), bounded by the ACTUAL
// component count ncr = 2048 - gcnt[0] (typically ~40-60, worst case 256)
// instead of the full 256 -- shrinks the serial single-CU tail's load,
// scan, and column loops by up to ~15x. Then the fused structure layer.
__global__ void __launch_bounds__(1024) k_finishstruct(float* __restrict__ ws,
                                                       const float* __restrict__ centres,
                                                       const float* __restrict__ sharp,
                                                       float* __restrict__ out) {
    __shared__ unsigned short Dcs[NC * NC];   // 128 KB
    __shared__ u64 cbf[NC];
    __shared__ unsigned parf[NC], ccomp[NC];
    __shared__ unsigned cnt_s, base_s;
    __shared__ float redlo[16], redhi[16];
    const int t = threadIdx.x;
    const int lane = t & 63, w = t >> 6;
    float* deaths = ws + DEATHS_OFF;
    const unsigned base0 = ((const unsigned*)(ws + GC_OFF))[0];

    if (base0 < B_N - 1) {
        const unsigned ncr = (unsigned)B_N - base0;   // remaining components <= 256
        const unsigned* gDc = (const unsigned*)(ws + DC_OFF);
        for (unsigned idx = (unsigned)t; idx < ncr * NC; idx += 1024u)
            Dcs[idx] = (unsigned short)(gDc[idx] >> 16);   // U32INF -> 0xFFFF
        if (t < NC) ccomp[t] = (unsigned)t;
        if (t == 0) base_s = base0;
        __syncthreads();
        const int HH = (int)((ncr + 63u) >> 6);           // col chunks of 64
        for (int iter = 0; iter < 8; ++iter) {
            if (t < NC) cbf[t] = U64MAX;
            if (t == 0) cnt_s = 0u;
            __syncthreads();
            // scan: rows interleaved across waves so small ncr stays balanced
            for (unsigned r = (unsigned)w; r < ncr; r += 16u) {
                const unsigned cc = ccomp[r];
                u64 key = U64MAX;
                for (int hh = 0; hh < HH; ++hh) {
                    const unsigned c = (unsigned)lane + (unsigned)hh * 64u;
                    unsigned wv = Dcs[r * NC + c];
                    if (wv != 0xFFFFu && ccomp[c] != cc) {
                        unsigned a = min(r, c);
                        unsigned b2 = max(r, c);
                        u64 k2 = ((u64)wv << 32) | (a << 8) | b2;
                        if (k2 < key) key = k2;
                    }
                }
                #pragma unroll
                for (int off = 32; off; off >>= 1) {
                    u64 o = __shfl_down(key, off);
                    if (o < key) key = o;
                }
                if (lane == 0 && key != U64MAX) atomicMin(&cbf[cc], key);
            }
            __syncthreads();
            bool add = false; float dw = 0.f;
            if (t < NC) {
                u64 k = cbf[t];
                unsigned p = (unsigned)t;
                if (k != U64MAX) {
                    unsigned a = (unsigned)((k >> 8) & 255u), b2 = (unsigned)(k & 255u);
                    unsigned ca = ccomp[a], cbv = ccomp[b2];
                    unsigned c2 = (ca == (unsigned)t) ? cbv : ca;
                    p = c2;
                    if (!(cbf[c2] == k && c2 < (unsigned)t)) {
                        add = true;
                        dw = __uint_as_float((unsigned)(k >> 32) << 16);
                    }
                }
                parf[t] = p;
            }
            __syncthreads();
            if (t < NC) {
                unsigned pp = parf[t];
                if (pp != (unsigned)t && parf[pp] == (unsigned)t && (unsigned)t < pp) parf[t] = (unsigned)t;
            }
            __syncthreads();
            if (t < NC) {
                unsigned r2 = parf[t];
                while (parf[r2] != r2) r2 = parf[r2];
                parf[t] = r2;
            }
            __syncthreads();
            if (t < NC) {
                if (add) { unsigned li = atomicAdd(&cnt_s, 1u); deaths[base_s + li] = dw; }
                ccomp[t] = parf[ccomp[t]];
            }
            __syncthreads();
            if (t == 0) base_s += cnt_s;
            __syncthreads();
            if (base_s >= B_N - 1) break;
        }
        __syncthreads();
    }

    // ---- struct phase ----
    float lo = INFINITY, hi = -INFINITY;
    #pragma unroll
    for (int i = t; i < B_N; i += 1024) {
        lo = fminf(lo, ws[BLO_OFF + i]);
        hi = fmaxf(hi, ws[BHI_OFF + i]);
    }
    #pragma unroll
    for (int off = 32; off; off >>= 1) {
        lo = fminf(lo, __shfl_down(lo, off));
        hi = fmaxf(hi, __shfl_down(hi, off));
    }
    if (lane == 0) { redlo[w] = lo; redhi[w] = hi; }
    __syncthreads();
    lo = redlo[0]; hi = redhi[0];
    #pragma unroll
    for (int k = 1; k < 16; ++k) { lo = fminf(lo, redlo[k]); hi = fmaxf(hi, redhi[k]); }
    float rng = hi - lo;
    float rinv = (rng > 1e-8f) ? 1.0f / rng : 0.0f;

    for (int e = w; e < E_N; e += 16) {
        const float c0 = centres[e * 2], c1 = centres[e * 2 + 1];
        const float s0 = sharp[e * 2],   s1 = sharp[e * 2 + 1];
        const float s1sq = s1 * s1;
        float acc = 0.f;
        for (int p = lane; p < B_N - 1; p += 64) {
            float d = deaths[p] * rinv - c1;
            acc += expf(-s1sq * d * d);
        }
        #pragma unroll
        for (int off = 32; off; off >>= 1) acc += __shfl_down(acc, off);
        if (lane == 0) out[e] = expf(-s0 * s0 * c0 * c0) * acc;
    }
}

extern "C" void kernel_launch(void* const* d_in, const int* in_sizes, int n_in,
                              void* d_out, int out_size, void* d_ws, size_t ws_size,
                              hipStream_t stream) {
    const float* x       = (const float*)d_in[0];
    const float* centres = (const float*)d_in[1];
    const float* sharp   = (const float*)d_in[2];
    float* out = (float*)d_out;
    float* ws  = (float*)d_ws;

    hipLaunchKernelGGL(k_reduce,   dim3(B_N),  dim3(256),  0, stream, x, ws);
    hipLaunchKernelGGL(k_distscan, dim3(256),  dim3(1024), 0, stream, ws);
    hipLaunchKernelGGL(k_round,    dim3(256),  dim3(1024), 0, stream, ws, 0);
    hipLaunchKernelGGL(k_round,    dim3(256),  dim3(1024), 0, stream, ws, 1);
    hipLaunchKernelGGL(k_round3c,  dim3(256),  dim3(1024), 0, stream, ws);
    hipLaunchKernelGGL(k_finishstruct, dim3(1), dim3(1024), 0, stream, ws, centres, sharp, out);
}